// Round 4
// baseline (427.413 us; speedup 1.0000x reference)
//
#include <hip/hip_runtime.h>
#include <hip/hip_bf16.h>

#define N_NODES 100000
#define N_EDGES 3200000
#define N_QUADS (N_EDGES / 4)            // 800000

// ---------------- workspace layout (bytes) ----------------
#define OFF_STATS 0                      // double[5] (zeroed)
#define OFF_DEG   1024                   // float[N]  (zeroed)
#define OFF_ACC   401024                 // float[N]  (encoder writes fully)
#define OFF_DINV  801024                 // float[N]
#define OFF_GS    1201024                // float[N]
// total ~1.6 MB

#define GRID_E 2048                      // edge-pass grid: 8 blocks/CU, 32 waves/CU
#define T_E    256

// per-wave int64-vs-int32 detection: high words of first 64 int64 slots
__device__ __forceinline__ bool detect_is64(const void* ei) {
    const int* p = (const int*)ei;
    int lane = threadIdx.x & 63;
    int hi = p[2 * lane + 1];
    unsigned long long m = __ballot(hi != 0);
    return m == 0ull;  // wave-uniform
}

// ---- K1: BN stats (over x) + degree via fire-and-forget global atomics ----
__global__ __launch_bounds__(T_E) void stats_deg_kernel(
        const float* __restrict__ x, const void* __restrict__ ei,
        double* __restrict__ stats, float* __restrict__ degf) {
    bool is64 = detect_is64(ei);
    int tid = blockIdx.x * T_E + threadIdx.x;
    const int STRIDE = GRID_E * T_E;

    // ---- degree: grid-stride over dst quads, unconditional atomics ----
    if (is64) {
        const long long* dstp = (const long long*)ei + N_EDGES;
        for (int q = tid; q < N_QUADS; q += STRIDE) {
            longlong2 d01 = ((const longlong2*)dstp)[2 * q];
            longlong2 d23 = ((const longlong2*)dstp)[2 * q + 1];
            unsafeAtomicAdd(&degf[(int)d01.x], 1.0f);
            unsafeAtomicAdd(&degf[(int)d01.y], 1.0f);
            unsafeAtomicAdd(&degf[(int)d23.x], 1.0f);
            unsafeAtomicAdd(&degf[(int)d23.y], 1.0f);
        }
    } else {
        const int* dstp = (const int*)ei + N_EDGES;
        for (int q = tid; q < N_QUADS; q += STRIDE) {
            int4 d4 = ((const int4*)dstp)[q];
            unsafeAtomicAdd(&degf[d4.x], 1.0f);
            unsafeAtomicAdd(&degf[d4.y], 1.0f);
            unsafeAtomicAdd(&degf[d4.z], 1.0f);
            unsafeAtomicAdd(&degf[d4.w], 1.0f);
        }
    }

    // ---- BN stats over x (blocks covering node range only; block-uniform guard) ----
    if (blockIdx.x * T_E < N_NODES) {
        __shared__ double sh[5][T_E / 64];
        int n = tid;
        double a0 = 0, a1 = 0, a2 = 0, a3 = 0, a4 = 0;
        if (n < N_NODES) {
            float2 v = ((const float2*)x)[n];
            double x0 = v.x, x1 = v.y;
            a0 = x0; a1 = x1; a2 = x0 * x0; a3 = x1 * x1; a4 = x0 * x1;
        }
        for (int off = 32; off; off >>= 1) {
            a0 += __shfl_down(a0, off);
            a1 += __shfl_down(a1, off);
            a2 += __shfl_down(a2, off);
            a3 += __shfl_down(a3, off);
            a4 += __shfl_down(a4, off);
        }
        int w = threadIdx.x >> 6;
        if ((threadIdx.x & 63) == 0) {
            sh[0][w] = a0; sh[1][w] = a1; sh[2][w] = a2; sh[3][w] = a3; sh[4][w] = a4;
        }
        __syncthreads();
        if (threadIdx.x == 0) {
            double t0 = 0, t1 = 0, t2 = 0, t3 = 0, t4 = 0;
            for (int i = 0; i < T_E / 64; i++) {
                t0 += sh[0][i]; t1 += sh[1][i]; t2 += sh[2][i]; t3 += sh[3][i]; t4 += sh[4][i];
            }
            atomicAdd(&stats[0], t0);
            atomicAdd(&stats[1], t1);
            atomicAdd(&stats[2], t2);
            atomicAdd(&stats[3], t3);
            atomicAdd(&stats[4], t4);
        }
    }
}

// ---- K2: encoder (unchanged math): gs[n] = dinv * (GB + sum_c PReLU(Ax0+Bx1+C) U[c]) ----
__global__ void encoder_kernel(const float* __restrict__ x,
                               const double* __restrict__ stats,
                               const float* __restrict__ w1, const float* __restrict__ b1,
                               const float* __restrict__ gamma, const float* __restrict__ beta,
                               const float* __restrict__ prelu_a,
                               const float* __restrict__ w2, const float* __restrict__ b2,
                               const float* __restrict__ gcn_w, const float* __restrict__ wb,
                               const float* __restrict__ degf,
                               float* __restrict__ dinv, float* __restrict__ gs,
                               float* __restrict__ acc) {
    __shared__ float sA[32], sB[32], sC[32], sV[32], sU[32];
    __shared__ float sGB;
    if (threadIdx.x < 32) {
        int c = threadIdx.x;
        double invN = 1.0 / (double)N_NODES;
        double m0 = stats[0] * invN, m1 = stats[1] * invN;
        double e00 = stats[2] * invN, e11 = stats[3] * invN, e01 = stats[4] * invN;
        double a = w1[2 * c], b = w1[2 * c + 1], t = b1[c];
        double meanH = a * m0 + b * m1 + t;
        double eh2 = a * a * e00 + b * b * e11 + 2.0 * a * b * e01 +
                     2.0 * t * (a * m0 + b * m1) + t * t;
        double var = eh2 - meanH * meanH;
        double inv = 1.0 / sqrt(var + 1e-5);
        float sc = (float)((double)gamma[c] * inv);
        float shift = beta[c] - (float)meanH * sc;
        sA[c] = (float)a * sc;
        sB[c] = (float)b * sc;
        sC[c] = (float)t * sc + shift;
        float vc = 0.f;
        for (int j = 0; j < 32; j++) vc += wb[j] * gcn_w[j * 32 + c];
        sV[c] = vc;
        float gb = b2[c] * vc;
        for (int off = 16; off; off >>= 1) gb += __shfl_down(gb, off, 32);
        if (c == 0) sGB = gb;
    }
    __syncthreads();
    if (threadIdx.x < 32) {
        float u = 0.f;
        for (int c = 0; c < 32; c++) u += sV[c] * w2[c * 32 + threadIdx.x];
        sU[threadIdx.x] = u;
    }
    __syncthreads();
    float alpha = prelu_a[0];
    int n = blockIdx.x * blockDim.x + threadIdx.x;
    if (n < N_NODES) {
        float2 xv = ((const float2*)x)[n];
        float g = sGB;
#pragma unroll
        for (int c = 0; c < 32; c++) {
            float hb = sA[c] * xv.x + sB[c] * xv.y + sC[c];
            float pc = hb >= 0.f ? hb : alpha * hb;
            g += pc * sU[c];
        }
        float di = rsqrtf(degf[n] + 1.0f);
        float gg = di * g;
        dinv[n] = di;
        gs[n] = gg;
        acc[n] = gg;  // self-loop term; finalize multiplies by dinv
    }
}

// ---- K3: scatter: acc[dst] += gs[src], fire-and-forget global atomics ----
__global__ __launch_bounds__(T_E) void scatter_kernel(
        const void* __restrict__ ei, const float* __restrict__ gs,
        float* __restrict__ acc) {
    bool is64 = detect_is64(ei);
    int tid = blockIdx.x * T_E + threadIdx.x;
    const int STRIDE = GRID_E * T_E;

    if (is64) {
        const long long* srcp = (const long long*)ei;
        const long long* dstp = srcp + N_EDGES;
        for (int q = tid; q < N_QUADS; q += STRIDE) {
            longlong2 s01 = ((const longlong2*)srcp)[2 * q];
            longlong2 s23 = ((const longlong2*)srcp)[2 * q + 1];
            longlong2 d01 = ((const longlong2*)dstp)[2 * q];
            longlong2 d23 = ((const longlong2*)dstp)[2 * q + 1];
            float g0 = gs[(int)s01.x];
            float g1 = gs[(int)s01.y];
            float g2 = gs[(int)s23.x];
            float g3 = gs[(int)s23.y];
            unsafeAtomicAdd(&acc[(int)d01.x], g0);
            unsafeAtomicAdd(&acc[(int)d01.y], g1);
            unsafeAtomicAdd(&acc[(int)d23.x], g2);
            unsafeAtomicAdd(&acc[(int)d23.y], g3);
        }
    } else {
        const int* srcp = (const int*)ei;
        const int* dstp = srcp + N_EDGES;
        for (int q = tid; q < N_QUADS; q += STRIDE) {
            int4 s4 = ((const int4*)srcp)[q];
            int4 d4 = ((const int4*)dstp)[q];
            float g0 = gs[s4.x];
            float g1 = gs[s4.y];
            float g2 = gs[s4.z];
            float g3 = gs[s4.w];
            unsafeAtomicAdd(&acc[d4.x], g0);
            unsafeAtomicAdd(&acc[d4.y], g1);
            unsafeAtomicAdd(&acc[d4.z], g2);
            unsafeAtomicAdd(&acc[d4.w], g3);
        }
    }
}

// ---- K4: finalize: out = dinv*acc + const ----
__global__ void finalize_kernel(const float* __restrict__ dinv, const float* __restrict__ acc,
                                const float* __restrict__ gcn_b, const float* __restrict__ wb,
                                const float* __restrict__ bb, float* __restrict__ out) {
    __shared__ float scc;
    if (threadIdx.x < 32) {
        float pv = wb[threadIdx.x] * gcn_b[threadIdx.x];
        for (int off = 16; off; off >>= 1) pv += __shfl_down(pv, off, 32);
        if (threadIdx.x == 0) scc = pv + bb[0];
    }
    __syncthreads();
    int n = blockIdx.x * blockDim.x + threadIdx.x;
    if (n < N_NODES) out[n] = dinv[n] * acc[n] + scc;
}

extern "C" void kernel_launch(void* const* d_in, const int* in_sizes, int n_in,
                              void* d_out, int out_size, void* d_ws, size_t ws_size,
                              hipStream_t stream) {
    const float* x       = (const float*)d_in[0];
    const void*  ei      = d_in[1];
    const float* w1      = (const float*)d_in[2];
    const float* b1      = (const float*)d_in[3];
    const float* bn_g    = (const float*)d_in[4];
    const float* bn_b    = (const float*)d_in[5];
    const float* prelu_a = (const float*)d_in[6];
    const float* w2      = (const float*)d_in[7];
    const float* b2      = (const float*)d_in[8];
    const float* gcn_w   = (const float*)d_in[9];
    const float* gcn_b   = (const float*)d_in[10];
    const float* wb      = (const float*)d_in[11];
    const float* bb      = (const float*)d_in[12];
    float* out = (float*)d_out;

    char* base = (char*)d_ws;
    double* stats = (double*)(base + OFF_STATS);
    float*  degf  = (float*)(base + OFF_DEG);
    float*  acc   = (float*)(base + OFF_ACC);
    float*  dinv  = (float*)(base + OFF_DINV);
    float*  gs    = (float*)(base + OFF_GS);

    // zero stats + degf (acc fully written by encoder)
    hipMemsetAsync(d_ws, 0, OFF_DEG + N_NODES * 4, stream);

    stats_deg_kernel<<<GRID_E, T_E, 0, stream>>>(x, ei, stats, degf);
    encoder_kernel<<<(N_NODES + 255) / 256, 256, 0, stream>>>(
        x, stats, w1, b1, bn_g, bn_b, prelu_a, w2, b2, gcn_w, wb, degf, dinv, gs, acc);
    scatter_kernel<<<GRID_E, T_E, 0, stream>>>(ei, gs, acc);
    finalize_kernel<<<(N_NODES + 255) / 256, 256, 0, stream>>>(dinv, acc, gcn_b, wb, bb, out);
}